// Round 1
// baseline (373.916 us; speedup 1.0000x reference)
//
#include <hip/hip_runtime.h>

// Pipeline: Conv2d(8->64,3x3,VALID) + bias -> GroupNorm(16) -> scale[c] -> MaxPool4x4 -> clip[0,1]
// x: [32,8,256,256] f32, out: [32,64,63,63] f32.
//
// Pass 1: tiled conv (computed once), per-(b,group) sum/sumsq via atomics into d_ws,
//         RAW 4x4-window maxima written into d_out (affine A>0 commutes with max).
// Pass 2: out = clamp(A[b,c]*raw + B[b,c], 0, 1) in place.

#define NPIX 258064.0f  // 4 * 254 * 254 elements per (b, group)

__global__ __launch_bounds__(256, 2) void conv_pool_stats(
    const float* __restrict__ x, const float* __restrict__ cw,
    const float* __restrict__ cb, float* __restrict__ pooled,
    float* __restrict__ stats)
{
    __shared__ float xs[8 * 34 * 36];   // [ic][34 rows][36-stride] 39.2 KB
    __shared__ float wl[8 * 9 * 64];    // [ic][k][c] 18.4 KB

    const int bx = blockIdx.x, by = blockIdx.y, b = blockIdx.z;
    const int tid = threadIdx.x;
    const int x0r = by * 32, x0c = bx * 32;

    // stage weights: cw[c][ic][kh][kw] -> wl[ic*9+k][c]  (coalesced global read)
    for (int i = tid; i < 4608; i += 256) {
        int c = i / 72; int rem = i - c * 72;       // rem = ic*9 + k
        wl[rem * 64 + c] = cw[i];
    }
    // stage x tile: 8 x 34 x 34, zero-padded out of range
    const float* xb = x + (size_t)b * 8 * 65536;
    for (int i = tid; i < 8 * 34 * 34; i += 256) {
        int ic = i / 1156; int rem = i - ic * 1156;
        int r = rem / 34;  int cc2 = rem - r * 34;
        int gr = x0r + r, gc = x0c + cc2;
        float v = 0.0f;
        if (gr < 256 && gc < 256) v = xb[ic * 65536 + gr * 256 + gc];
        xs[ic * 1224 + r * 36 + cc2] = v;
    }
    __syncthreads();

    const int cell = tid & 63;
    const int px = cell & 7, py = cell >> 3;
    const int cc = tid >> 6;                 // channel quarter: 16 channels
    const int lr = py * 4, lc = px * 4;      // local y-tile coords
    const int yrow0 = x0r + lr, ycol0 = x0c + lc;
    const int nh = min(4, 254 - yrow0);      // valid rows in this pool window (>=2)
    const int nw = min(4, 254 - ycol0);
    const int pyg = by * 8 + py, pxg = bx * 8 + px;
    const bool wr = (pyg < 63) && (pxg < 63);

    #pragma unroll 1
    for (int chunk = 0; chunk < 4; ++chunk) {   // 4 channels / iter == one group
        const int c0 = cc * 16 + chunk * 4;
        const float4 bias = *reinterpret_cast<const float4*>(cb + c0);
        float acc0[16], acc1[16], acc2[16], acc3[16];
        #pragma unroll
        for (int p = 0; p < 16; ++p) {
            acc0[p] = bias.x; acc1[p] = bias.y; acc2[p] = bias.z; acc3[p] = bias.w;
        }
        #pragma unroll 1
        for (int ic = 0; ic < 8; ++ic) {
            float xv[36];
            const float* xrow = xs + ic * 1224 + lr * 36 + lc;
            #pragma unroll
            for (int r = 0; r < 6; ++r) {
                float4 a  = *reinterpret_cast<const float4*>(xrow + r * 36);
                float2 b2 = *reinterpret_cast<const float2*>(xrow + r * 36 + 4);
                xv[r*6+0] = a.x;  xv[r*6+1] = a.y; xv[r*6+2] = a.z; xv[r*6+3] = a.w;
                xv[r*6+4] = b2.x; xv[r*6+5] = b2.y;
            }
            const float* wbase = wl + ic * 9 * 64 + c0;
            #pragma unroll
            for (int kh = 0; kh < 3; ++kh) {
                #pragma unroll
                for (int kw = 0; kw < 3; ++kw) {
                    const float4 w = *reinterpret_cast<const float4*>(wbase + (kh*3+kw) * 64);
                    #pragma unroll
                    for (int ph = 0; ph < 4; ++ph) {
                        #pragma unroll
                        for (int pw = 0; pw < 4; ++pw) {
                            const float xval = xv[(ph+kh)*6 + (pw+kw)];
                            const int p = ph*4 + pw;
                            acc0[p] = fmaf(xval, w.x, acc0[p]);
                            acc1[p] = fmaf(xval, w.y, acc1[p]);
                            acc2[p] = fmaf(xval, w.z, acc2[p]);
                            acc3[p] = fmaf(xval, w.w, acc3[p]);
                        }
                    }
                }
            }
        }
        // epilogue: stats (valid pixels only) + raw window max
        float s = 0.0f, q = 0.0f;
        float m0 = -3.4e38f, m1 = -3.4e38f, m2 = -3.4e38f, m3 = -3.4e38f;
        #pragma unroll
        for (int ph = 0; ph < 4; ++ph) {
            #pragma unroll
            for (int pw = 0; pw < 4; ++pw) {
                const int p = ph*4 + pw;
                const bool valid = (ph < nh) && (pw < nw);
                const float v0 = valid ? acc0[p] : 0.0f;
                const float v1 = valid ? acc1[p] : 0.0f;
                const float v2 = valid ? acc2[p] : 0.0f;
                const float v3 = valid ? acc3[p] : 0.0f;
                s += (v0 + v1) + (v2 + v3);
                q += (v0*v0 + v1*v1) + (v2*v2 + v3*v3);
                m0 = valid ? fmaxf(m0, acc0[p]) : m0;
                m1 = valid ? fmaxf(m1, acc1[p]) : m1;
                m2 = valid ? fmaxf(m2, acc2[p]) : m2;
                m3 = valid ? fmaxf(m3, acc3[p]) : m3;
            }
        }
        if (wr) {
            const int obase = ((b * 64 + c0) * 63 + pyg) * 63 + pxg;
            pooled[obase]          = m0;
            pooled[obase + 3969]   = m1;
            pooled[obase + 2*3969] = m2;
            pooled[obase + 3*3969] = m3;
        }
        // wave-reduce s,q (all 64 lanes share cc => same group)
        #pragma unroll
        for (int off = 1; off < 64; off <<= 1) {
            s += __shfl_xor(s, off, 64);
            q += __shfl_xor(q, off, 64);
        }
        if ((tid & 63) == 0) {
            const int g = cc * 4 + chunk;
            atomicAdd(&stats[b * 16 + g], s);
            atomicAdd(&stats[512 + b * 16 + g], q);
        }
    }
}

__global__ __launch_bounds__(256) void finalize_affine_clamp(
    float* __restrict__ out, const float* __restrict__ stats,
    const float* __restrict__ gnw, const float* __restrict__ gnb,
    const float* __restrict__ scale)
{
    const int i = blockIdx.x * 256 + threadIdx.x;
    if (i >= 32 * 64 * 63 * 63) return;
    const int bc = i / 3969;
    const int b = bc >> 6, c = bc & 63, g = c >> 2;
    const float sum = stats[b * 16 + g];
    const float ssq = stats[512 + b * 16 + g];
    const float invN = 1.0f / NPIX;
    const float mean = sum * invN;
    const float var  = ssq * invN - mean * mean;
    const float rs   = rsqrtf(var + 1e-5f);
    const float A  = rs * gnw[c] * scale[c];
    const float Bv = (gnb[c] - mean * rs * gnw[c]) * scale[c];
    float v = fmaf(A, out[i], Bv);
    v = fminf(fmaxf(v, 0.0f), 1.0f);
    out[i] = v;
}

extern "C" void kernel_launch(void* const* d_in, const int* in_sizes, int n_in,
                              void* d_out, int out_size, void* d_ws, size_t ws_size,
                              hipStream_t stream) {
    const float* x     = (const float*)d_in[0];
    const float* cw    = (const float*)d_in[1];
    const float* cb    = (const float*)d_in[2];
    const float* gnw   = (const float*)d_in[3];
    const float* gnb   = (const float*)d_in[4];
    const float* scale = (const float*)d_in[5];
    float* out   = (float*)d_out;
    float* stats = (float*)d_ws;

    hipMemsetAsync(d_ws, 0, 1024 * sizeof(float), stream);

    dim3 grid1(8, 8, 32);
    conv_pool_stats<<<grid1, 256, 0, stream>>>(x, cw, cb, out, stats);

    const int total = 32 * 64 * 63 * 63;
    finalize_affine_clamp<<<(total + 255) / 256, 256, 0, stream>>>(out, stats, gnw, gnb, scale);
}

// Round 2
// 322.881 us; speedup vs baseline: 1.1581x; 1.1581x over previous
//
#include <hip/hip_runtime.h>

// Pipeline: Conv2d(8->64,3x3,VALID)+bias -> GroupNorm(16) -> scale[c] -> MaxPool4x4 -> clip[0,1]
// x: [32,8,256,256] f32 -> out: [32,64,63,63] f32.
//
// Pass 1 (conv_pool_stats): tiled conv computed ONCE; per-(b,group) sum/sumsq via
//   wave-reduce + atomics into d_ws; RAW 4x4-window maxima -> d_out.
//   (GN+scale is affine with A>0, so maxpool commutes: max(A*y+B) = A*max(y)+B.)
// Pass 2 (finalize): out = clamp(A*raw + B, 0, 1), float4-vectorized, in place.
//
// R2 changes vs R1 (reg pressure + occupancy):
//  - stream x rows (6 floats live) instead of 36-elem patch -> ~90 live VGPRs, no spills
//  - weights via readfirstlane->s_load into SGPRs (drops 18.4KB weight LDS)
//  - xs-only LDS 39.2KB -> 4 blocks/CU (16 waves/CU)

#define NPIX 258064.0f  // 4 * 254 * 254 elements per (b, group)

__device__ __forceinline__ float rfl_f32(float x) {
    return __int_as_float(__builtin_amdgcn_readfirstlane(__float_as_int(x)));
}

__global__ __launch_bounds__(256, 4) void conv_pool_stats(
    const float* __restrict__ x, const float* __restrict__ cw,
    const float* __restrict__ cb, float* __restrict__ pooled,
    float* __restrict__ stats)
{
    __shared__ float xs[8 * 34 * 36];   // [ic][34 rows][36-float stride] = 39168 B

    const int bx = blockIdx.x, by = blockIdx.y, b = blockIdx.z;
    const int tid = threadIdx.x;
    const int x0r = by * 32, x0c = bx * 32;

    // stage x tile: 8 x 34 x 34 (float4 granules; cols 34-35 are never-read pad)
    const float* xb = x + (size_t)b * 8 * 65536;
    for (int i = tid; i < 8 * 34 * 9; i += 256) {
        int ic = i / 306; int rem = i - ic * 306;
        int r = rem / 9;  int g = rem - r * 9;
        int gr = x0r + r, gc0 = x0c + 4 * g;
        float4 v = make_float4(0.f, 0.f, 0.f, 0.f);
        if (gr < 256 && gc0 < 256)   // aligned float4, never straddles row end
            v = *reinterpret_cast<const float4*>(xb + ic * 65536 + gr * 256 + gc0);
        *reinterpret_cast<float4*>(xs + ic * 1224 + r * 36 + 4 * g) = v;
    }
    __syncthreads();

    const int cell = tid & 63;
    const int px = cell & 7, py = cell >> 3;
    const int cc = tid >> 6;                 // channel quarter (uniform per wave)
    const int lr = py * 4, lc = px * 4;
    const int yrow0 = x0r + lr, ycol0 = x0c + lc;
    const int nh = min(4, 254 - yrow0);      // valid rows in this pool window
    const int nw = min(4, 254 - ycol0);
    const int pyg = by * 8 + py, pxg = bx * 8 + px;
    const bool wr = (pyg < 63) && (pxg < 63);

    #pragma unroll 1
    for (int chunk = 0; chunk < 4; ++chunk) {   // 4 channels / iter == one GN group
        const int c0 = __builtin_amdgcn_readfirstlane((tid >> 6) * 16 + chunk * 4);
        const float b0 = rfl_f32(cb[c0]);
        const float b1 = rfl_f32(cb[c0 + 1]);
        const float b2v = rfl_f32(cb[c0 + 2]);
        const float b3 = rfl_f32(cb[c0 + 3]);
        float acc0[16], acc1[16], acc2[16], acc3[16];
        #pragma unroll
        for (int p = 0; p < 16; ++p) {
            acc0[p] = b0; acc1[p] = b1; acc2[p] = b2v; acc3[p] = b3;
        }
        #pragma unroll 1
        for (int ic = 0; ic < 8; ++ic) {
            // weights for 4 channels x 9 taps -> scalar regs
            const int sb = __builtin_amdgcn_readfirstlane(c0 * 72 + ic * 9);
            float ws0[9], ws1[9], ws2[9], ws3[9];
            #pragma unroll
            for (int k = 0; k < 9; ++k) {
                ws0[k] = rfl_f32(cw[sb + k]);
                ws1[k] = rfl_f32(cw[sb + 72 + k]);
                ws2[k] = rfl_f32(cw[sb + 144 + k]);
                ws3[k] = rfl_f32(cw[sb + 216 + k]);
            }
            const float* xrow = xs + ic * 1224 + lr * 36 + lc;
            #pragma unroll
            for (int r = 0; r < 6; ++r) {     // stream input rows
                float4 a  = *reinterpret_cast<const float4*>(xrow + r * 36);
                float2 bb = *reinterpret_cast<const float2*>(xrow + r * 36 + 4);
                float xv[6] = {a.x, a.y, a.z, a.w, bb.x, bb.y};
                #pragma unroll
                for (int kh = 0; kh < 3; ++kh) {
                    const int ph = r - kh;
                    if (ph < 0 || ph > 3) continue;
                    #pragma unroll
                    for (int kw = 0; kw < 3; ++kw) {
                        const int wk = kh * 3 + kw;
                        #pragma unroll
                        for (int pw = 0; pw < 4; ++pw) {
                            const float xval = xv[pw + kw];
                            const int p = ph * 4 + pw;
                            acc0[p] = fmaf(xval, ws0[wk], acc0[p]);
                            acc1[p] = fmaf(xval, ws1[wk], acc1[p]);
                            acc2[p] = fmaf(xval, ws2[wk], acc2[p]);
                            acc3[p] = fmaf(xval, ws3[wk], acc3[p]);
                        }
                    }
                }
            }
        }
        // epilogue: stats over valid pixels + raw window max
        float s = 0.0f, q = 0.0f;
        float m0 = -3.4e38f, m1 = -3.4e38f, m2 = -3.4e38f, m3 = -3.4e38f;
        #pragma unroll
        for (int ph = 0; ph < 4; ++ph) {
            #pragma unroll
            for (int pw = 0; pw < 4; ++pw) {
                const int p = ph * 4 + pw;
                const bool valid = (ph < nh) && (pw < nw);
                const float v0 = valid ? acc0[p] : 0.0f;
                const float v1 = valid ? acc1[p] : 0.0f;
                const float v2 = valid ? acc2[p] : 0.0f;
                const float v3 = valid ? acc3[p] : 0.0f;
                s += (v0 + v1) + (v2 + v3);
                q += (v0 * v0 + v1 * v1) + (v2 * v2 + v3 * v3);
                m0 = valid ? fmaxf(m0, acc0[p]) : m0;
                m1 = valid ? fmaxf(m1, acc1[p]) : m1;
                m2 = valid ? fmaxf(m2, acc2[p]) : m2;
                m3 = valid ? fmaxf(m3, acc3[p]) : m3;
            }
        }
        if (wr) {
            const int obase = ((b * 64 + c0) * 63 + pyg) * 63 + pxg;
            pooled[obase]            = m0;
            pooled[obase + 3969]     = m1;
            pooled[obase + 2 * 3969] = m2;
            pooled[obase + 3 * 3969] = m3;
        }
        #pragma unroll
        for (int off = 1; off < 64; off <<= 1) {
            s += __shfl_xor(s, off, 64);
            q += __shfl_xor(q, off, 64);
        }
        if ((tid & 63) == 0) {
            const int g = (tid >> 6) * 4 + chunk;
            atomicAdd(&stats[b * 16 + g], s);
            atomicAdd(&stats[512 + b * 16 + g], q);
        }
    }
}

__global__ __launch_bounds__(256) void finalize_affine_clamp(
    float* __restrict__ out, const float* __restrict__ stats,
    const float* __restrict__ gnw, const float* __restrict__ gnb,
    const float* __restrict__ scale)
{
    const int i4 = blockIdx.x * 256 + threadIdx.x;
    if (i4 >= (32 * 64 * 3969) / 4) return;
    float4 v = reinterpret_cast<float4*>(out)[i4];
    float r[4] = {v.x, v.y, v.z, v.w};
    #pragma unroll
    for (int j = 0; j < 4; ++j) {
        const int i = i4 * 4 + j;
        const int bc = i / 3969;
        const int b = bc >> 6, c = bc & 63, g = c >> 2;
        const float sum = stats[b * 16 + g];
        const float ssq = stats[512 + b * 16 + g];
        const float invN = 1.0f / NPIX;
        const float mean = sum * invN;
        const float var  = ssq * invN - mean * mean;
        const float rs   = rsqrtf(var + 1e-5f);
        const float A  = rs * gnw[c] * scale[c];
        const float Bv = (gnb[c] - mean * rs * gnw[c]) * scale[c];
        float t = fmaf(A, r[j], Bv);
        r[j] = fminf(fmaxf(t, 0.0f), 1.0f);
    }
    reinterpret_cast<float4*>(out)[i4] = make_float4(r[0], r[1], r[2], r[3]);
}

extern "C" void kernel_launch(void* const* d_in, const int* in_sizes, int n_in,
                              void* d_out, int out_size, void* d_ws, size_t ws_size,
                              hipStream_t stream) {
    const float* x     = (const float*)d_in[0];
    const float* cw    = (const float*)d_in[1];
    const float* cb    = (const float*)d_in[2];
    const float* gnw   = (const float*)d_in[3];
    const float* gnb   = (const float*)d_in[4];
    const float* scale = (const float*)d_in[5];
    float* out   = (float*)d_out;
    float* stats = (float*)d_ws;

    hipMemsetAsync(d_ws, 0, 1024 * sizeof(float), stream);

    dim3 grid1(8, 8, 32);
    conv_pool_stats<<<grid1, 256, 0, stream>>>(x, cw, cb, out, stats);

    const int total4 = (32 * 64 * 3969) / 4;
    finalize_affine_clamp<<<(total4 + 255) / 256, 256, 0, stream>>>(out, stats, gnw, gnb, scale);
}